// Round 1
// baseline (185.041 us; speedup 1.0000x reference)
//
#include <hip/hip_runtime.h>

typedef float v4f __attribute__((ext_vector_type(4)));
typedef short v8s __attribute__((ext_vector_type(8)));
typedef unsigned short v4us __attribute__((ext_vector_type(4)));

#define BM 128

__device__ __forceinline__ unsigned short f2bf(float f) {
    union { float f; unsigned u; } v; v.f = f;
    unsigned u = v.u;
    u += 0x7FFFu + ((u >> 16) & 1u);   // round-to-nearest-even
    return (unsigned short)(u >> 16);
}

__device__ __forceinline__ float fast_exp2(float x) {
#if __has_builtin(__builtin_amdgcn_exp2f)
    return __builtin_amdgcn_exp2f(x);
#else
    return exp2f(x);
#endif
}
__device__ __forceinline__ float fast_rcp(float x) {
#if __has_builtin(__builtin_amdgcn_rcpf)
    return __builtin_amdgcn_rcpf(x);
#else
    return 1.0f / x;
#endif
}
__device__ __forceinline__ float fast_tanh(float y) {
    // tanh(y) = (e^{2y}-1)/(e^{2y}+1);  |y| <= ~10 here, no overflow
    float t = fast_exp2(y * 2.885390081777927f);
    return (t - 1.0f) * fast_rcp(t + 1.0f);
}
__device__ __forceinline__ float fast_sigmoid(float z) {
    float t = fast_exp2(-1.4426950408889634f * z);
    return fast_rcp(1.0f + t);
}

// ---------------------------------------------------------------------------
// Pack 5 weight matrices (fp32 row-major [N][K]) into bf16 MFMA-B-fragment
// order: elem (n,k) -> ((nt*(K/32)+ks)*64 + ((k>>3)&3)*16 + (n&15))*8 + (k&7)
// so a wave's B-fragment load is 64 lanes x 16B fully contiguous.
// ws layout: Wb(98304) | W1(65536) | W2 | Wa | Wt   (bf16 elems)
// ---------------------------------------------------------------------------
__global__ void prep_pack(const float* __restrict__ Wb, const float* __restrict__ W1,
                          const float* __restrict__ W2, const float* __restrict__ Wa,
                          const float* __restrict__ Wt, unsigned short* __restrict__ ws)
{
    int e = blockIdx.x * 256 + threadIdx.x;
    if (e >= 360448) return;
    const float* src; int K; int base;
    if (e < 98304)       { src = Wb; K = 384; base = 0; }
    else if (e < 163840) { src = W1; K = 256; base = 98304; }
    else if (e < 229376) { src = W2; K = 256; base = 163840; }
    else if (e < 294912) { src = Wa; K = 256; base = 229376; }
    else                 { src = Wt; K = 256; base = 294912; }
    int le   = e - base;
    int j    = le & 7;
    int lane = (le >> 3) & 63;
    int tile = le >> 9;
    int kt   = K >> 5;
    int ks   = tile % kt;
    int nt   = tile / kt;
    int n = nt * 16 + (lane & 15);
    int k = ks * 32 + (lane >> 4) * 8 + j;
    ws[e] = f2bf(src[n * K + k]);
}

// ---------------------------------------------------------------------------
// Fused CfC cell: phase 1  X = lecun_tanh([in|hx] @ Wb^T + bb)   (K=384)
//                 phase 2  4 simultaneous GEMMs over X (K=256) + fused epilogue
// 512 blocks x 256 threads (4 waves as 2x2); BM=128 rows; LDS=64KB (2 blk/CU)
// ---------------------------------------------------------------------------
__global__ __launch_bounds__(256, 2) void cfc_fused(
    const float* __restrict__ xin, const float* __restrict__ hx,
    const float* __restrict__ ts,
    const float* __restrict__ bb, const float* __restrict__ b1,
    const float* __restrict__ b2, const float* __restrict__ ba,
    const float* __restrict__ bt,
    const unsigned short* __restrict__ wpk,
    float* __restrict__ out)
{
    __shared__ unsigned short lds[32768];   // 64 KB: A-chunk (32KB) then X (64KB)
    const int tid  = threadIdx.x;
    const int lane = tid & 63;
    const int wid  = tid >> 6;
    const int wr   = wid >> 1;      // wave row (0..1): 64 rows each
    const int wc   = wid & 1;       // wave col (0..1): 128 cols each
    const int row0 = blockIdx.x * BM;

    // ---------------- phase 1: backbone GEMM, acc[n-tile][m-tile] -----------
    v4f acc[8][4];
    #pragma unroll
    for (int nt = 0; nt < 8; ++nt) {
        float bv = bb[wc * 128 + nt * 16 + (lane & 15)];
        v4f bvv = {bv, bv, bv, bv};
        #pragma unroll
        for (int mt = 0; mt < 4; ++mt) acc[nt][mt] = bvv;
    }

    for (int c = 0; c < 3; ++c) {   // K chunks: in[0:128], hx[0:128], hx[128:256]
        const float* src = (c == 0) ? (xin + (size_t)row0 * 128)
                                    : (hx + (size_t)row0 * 256 + (c == 2 ? 128 : 0));
        const int srcld = (c == 0) ? 128 : 256;
        __syncthreads();            // previous chunk fully consumed
        #pragma unroll
        for (int it = 0; it < 16; ++it) {
            int i  = tid + it * 256;        // 0..4095 float4s of a 128x128 tile
            int r  = i >> 5;
            int c4 = i & 31;
            v4f v = *(reinterpret_cast<const v4f*>(src + (size_t)r * srcld) + c4);
            v4us pk;
            pk[0] = f2bf(v[0]); pk[1] = f2bf(v[1]); pk[2] = f2bf(v[2]); pk[3] = f2bf(v[3]);
            int idx = (((r >> 4) * 4 + (c4 >> 3)) * 64 + ((c4 >> 1) & 3) * 16 + (r & 15)) * 8
                      + (c4 & 1) * 4;
            *reinterpret_cast<v4us*>(&lds[idx]) = pk;
        }
        __syncthreads();
        #pragma unroll
        for (int ksl = 0; ksl < 4; ++ksl) {
            v8s a[4];
            #pragma unroll
            for (int mt = 0; mt < 4; ++mt)
                a[mt] = *reinterpret_cast<const v8s*>(&lds[(((wr*4 + mt)*4 + ksl)*64 + lane)*8]);
            const int gks = c * 4 + ksl;
            #pragma unroll
            for (int nt = 0; nt < 8; ++nt) {
                v8s b = *reinterpret_cast<const v8s*>(
                            wpk + ((size_t)((wc*8 + nt)*12 + gks)*64 + lane)*8);
                #pragma unroll
                for (int mt = 0; mt < 4; ++mt)
                    acc[nt][mt] = __builtin_amdgcn_mfma_f32_16x16x32_bf16(a[mt], b, acc[nt][mt], 0, 0, 0);
            }
        }
    }
    __syncthreads();

    // ------------- activation + write X to LDS in packed A-frag layout ------
    // D elem: row = wr*64+mt*16+(lane>>4)*4+r, col(k2) = wc*128+nt*16+(lane&15)
    #pragma unroll
    for (int nt = 0; nt < 8; ++nt)
        #pragma unroll
        for (int mt = 0; mt < 4; ++mt)
            #pragma unroll
            for (int r = 0; r < 4; ++r) {
                float xv = 1.7159f * fast_tanh(0.666f * acc[nt][mt][r]);
                int idx = ((((wr*4 + mt)*8) + wc*4 + (nt >> 1)) * 64
                           + ((nt & 1)*2 + ((lane >> 3) & 1)) * 16 + (lane >> 4)*4 + r) * 8
                          + (lane & 7);
                lds[idx] = f2bf(xv);
            }
    __syncthreads();

    // ---------------- phase 2: 4 GEMMs over X + fused epilogue --------------
    const unsigned short* wmp = wpk + 98304;   // W1,W2,Wa,Wt each 65536 elems
    for (int g = 0; g < 4; ++g) {              // n-tile pairs
        v4f a2[2][4][4];                       // [ntp][mat][mt]
        #pragma unroll
        for (int ntp = 0; ntp < 2; ++ntp) {
            int n = wc * 128 + (g*2 + ntp) * 16 + (lane & 15);
            float v1 = b1[n], v2 = b2[n], va = ba[n], vt = bt[n];
            v4f q1 = {v1,v1,v1,v1}, q2 = {v2,v2,v2,v2}, qa = {va,va,va,va}, qt = {vt,vt,vt,vt};
            #pragma unroll
            for (int mt = 0; mt < 4; ++mt) {
                a2[ntp][0][mt] = q1; a2[ntp][1][mt] = q2;
                a2[ntp][2][mt] = qa; a2[ntp][3][mt] = qt;
            }
        }
        for (int ks = 0; ks < 8; ++ks) {
            v8s a[4];
            #pragma unroll
            for (int mt = 0; mt < 4; ++mt)
                a[mt] = *reinterpret_cast<const v8s*>(&lds[(((wr*4 + mt)*8 + ks)*64 + lane)*8]);
            #pragma unroll
            for (int ntp = 0; ntp < 2; ++ntp) {
                int tile = ((wc*8 + g*2 + ntp)*8 + ks)*64;
                #pragma unroll
                for (int mat = 0; mat < 4; ++mat) {
                    v8s b = *reinterpret_cast<const v8s*>(wmp + (size_t)mat*65536 + ((size_t)tile + lane)*8);
                    #pragma unroll
                    for (int mt = 0; mt < 4; ++mt)
                        a2[ntp][mat][mt] = __builtin_amdgcn_mfma_f32_16x16x32_bf16(a[mt], b, a2[ntp][mat][mt], 0, 0, 0);
                }
            }
        }
        // fused epilogue: ff1, ff2, t_interp, blend, store
        #pragma unroll
        for (int ntp = 0; ntp < 2; ++ntp) {
            int coln = wc * 128 + (g*2 + ntp) * 16 + (lane & 15);
            #pragma unroll
            for (int mt = 0; mt < 4; ++mt) {
                int rowb = row0 + wr*64 + mt*16 + ((lane >> 4) << 2);
                #pragma unroll
                for (int r = 0; r < 4; ++r) {
                    float tsv = ts[rowb + r];
                    float ff1 = fast_tanh(a2[ntp][0][mt][r]);
                    float ff2 = fast_tanh(a2[ntp][1][mt][r]);
                    float ti  = fast_sigmoid(a2[ntp][2][mt][r] * tsv + a2[ntp][3][mt][r]);
                    out[(size_t)(rowb + r) * 256 + coln] = ff1 + ti * (ff2 - ff1);
                }
            }
        }
    }
}

extern "C" void kernel_launch(void* const* d_in, const int* in_sizes, int n_in,
                              void* d_out, int out_size, void* d_ws, size_t ws_size,
                              hipStream_t stream)
{
    const float* xin = (const float*)d_in[0];
    const float* hx  = (const float*)d_in[1];
    const float* ts  = (const float*)d_in[2];
    const float* Wb  = (const float*)d_in[3];
    const float* bb  = (const float*)d_in[4];
    const float* W1  = (const float*)d_in[5];
    const float* b1  = (const float*)d_in[6];
    const float* W2  = (const float*)d_in[7];
    const float* b2  = (const float*)d_in[8];
    const float* Wa  = (const float*)d_in[9];
    const float* ba  = (const float*)d_in[10];
    const float* Wt  = (const float*)d_in[11];
    const float* bt  = (const float*)d_in[12];

    if (ws_size < 360448 * sizeof(unsigned short)) return;
    unsigned short* wpk = (unsigned short*)d_ws;

    prep_pack<<<1408, 256, 0, stream>>>(Wb, W1, W2, Wa, Wt, wpk);
    cfc_fused<<<512, 256, 0, stream>>>(xin, hx, ts, bb, b1, b2, ba, bt, wpk,
                                       (float*)d_out);
}

// Round 2
// 94.879 us; speedup vs baseline: 1.9503x; 1.9503x over previous
//
#include <hip/hip_runtime.h>

typedef float v4f __attribute__((ext_vector_type(4)));
typedef short v8s __attribute__((ext_vector_type(8)));
typedef unsigned short v4us __attribute__((ext_vector_type(4)));

#define BM 64

__device__ __forceinline__ unsigned short f2bf(float f) {
    union { float f; unsigned u; } v; v.f = f;
    unsigned u = v.u;
    u += 0x7FFFu + ((u >> 16) & 1u);   // round-to-nearest-even
    return (unsigned short)(u >> 16);
}

__device__ __forceinline__ float fast_exp2(float x) {
#if __has_builtin(__builtin_amdgcn_exp2f)
    return __builtin_amdgcn_exp2f(x);
#else
    return exp2f(x);
#endif
}
__device__ __forceinline__ float fast_rcp(float x) {
#if __has_builtin(__builtin_amdgcn_rcpf)
    return __builtin_amdgcn_rcpf(x);
#else
    return 1.0f / x;
#endif
}
__device__ __forceinline__ float fast_tanh(float y) {
    float t = fast_exp2(y * 2.885390081777927f);
    return (t - 1.0f) * fast_rcp(t + 1.0f);
}
__device__ __forceinline__ float fast_sigmoid(float z) {
    float t = fast_exp2(-1.4426950408889634f * z);
    return fast_rcp(1.0f + t);
}

// ---------------------------------------------------------------------------
// Pack 5 weight matrices (fp32 row-major [N][K]) into bf16 MFMA-B-fragment
// order (canonical 16x32 tile: lane = ((k>>3)&3)*16 + (n&15), j = k&7).
// ws layout: Wb(98304) | W1(65536) | W2 | Wa | Wt   (bf16 elems)
// ---------------------------------------------------------------------------
__global__ void prep_pack(const float* __restrict__ Wb, const float* __restrict__ W1,
                          const float* __restrict__ W2, const float* __restrict__ Wa,
                          const float* __restrict__ Wt, unsigned short* __restrict__ ws)
{
    int e = blockIdx.x * 256 + threadIdx.x;
    if (e >= 360448) return;
    const float* src; int K; int base;
    if (e < 98304)       { src = Wb; K = 384; base = 0; }
    else if (e < 163840) { src = W1; K = 256; base = 98304; }
    else if (e < 229376) { src = W2; K = 256; base = 163840; }
    else if (e < 294912) { src = Wa; K = 256; base = 229376; }
    else                 { src = Wt; K = 256; base = 294912; }
    int le   = e - base;
    int j    = le & 7;
    int lane = (le >> 3) & 63;
    int tile = le >> 9;
    int kt   = K >> 5;
    int ks   = tile % kt;
    int nt   = tile / kt;
    int n = nt * 16 + (lane & 15);
    int k = ks * 32 + (lane >> 4) * 8 + j;
    ws[e] = f2bf(src[n * K + k]);
}

// ---------------------------------------------------------------------------
// Fused CfC cell, BM=64 rows/block, 4 waves each owning 64 output cols.
// LDS 32KB (staging 16KB overlaid by X 32KB) -> 4 blocks/CU = 16 waves/CU.
// phase 1: X = lecun_tanh([in|hx] @ Wb^T + bb)   (K=384)
// phase 2: 4 simultaneous GEMMs over X (K=256) + fused epilogue
// ---------------------------------------------------------------------------
__global__ __launch_bounds__(256, 4) void cfc_fused(
    const float* __restrict__ xin, const float* __restrict__ hx,
    const float* __restrict__ ts,
    const float* __restrict__ bb, const float* __restrict__ b1,
    const float* __restrict__ b2, const float* __restrict__ ba,
    const float* __restrict__ bt,
    const unsigned short* __restrict__ wpk,
    float* __restrict__ out)
{
    __shared__ unsigned short lds[16384];   // 32 KB
    const int tid  = threadIdx.x;
    const int lane = tid & 63;
    const int w    = tid >> 6;        // wave id = output-col group (64 cols)
    const int row0 = blockIdx.x * BM;

    // ---------------- phase 1: backbone GEMM, acc[nt][mt] -------------------
    v4f acc[4][4];
    #pragma unroll
    for (int nt = 0; nt < 4; ++nt) {
        float bv = bb[w * 64 + nt * 16 + (lane & 15)];
        v4f bvv = {bv, bv, bv, bv};
        #pragma unroll
        for (int mt = 0; mt < 4; ++mt) acc[nt][mt] = bvv;
    }

    for (int c = 0; c < 3; ++c) {   // K chunks: in[0:128], hx[0:128], hx[128:256]
        const float* src = (c == 0) ? (xin + (size_t)row0 * 128)
                                    : (hx + (size_t)row0 * 256 + (c == 2 ? 128 : 0));
        const int srcld = (c == 0) ? 128 : 256;
        __syncthreads();            // previous chunk fully consumed
        #pragma unroll
        for (int it = 0; it < 8; ++it) {
            int i  = tid + it * 256;        // 0..2047 float4s of a 64x128 tile
            int r  = i >> 5;
            int c4 = i & 31;
            v4f v = *(reinterpret_cast<const v4f*>(src + (size_t)r * srcld) + c4);
            v4us pk;
            pk[0] = f2bf(v[0]); pk[1] = f2bf(v[1]); pk[2] = f2bf(v[2]); pk[3] = f2bf(v[3]);
            int idx = (((r >> 4) * 4 + (c4 >> 3)) * 64 + ((c4 >> 1) & 3) * 16 + (r & 15)) * 8
                      + (c4 & 1) * 4;
            *reinterpret_cast<v4us*>(&lds[idx]) = pk;
        }
        __syncthreads();
        #pragma unroll 1
        for (int ksl = 0; ksl < 4; ++ksl) {
            v8s a[4];
            #pragma unroll
            for (int mt = 0; mt < 4; ++mt)
                a[mt] = *reinterpret_cast<const v8s*>(&lds[((mt*4 + ksl)*64 + lane)*8]);
            const int gks = c * 4 + ksl;
            #pragma unroll
            for (int nt = 0; nt < 4; ++nt) {
                v8s b = *reinterpret_cast<const v8s*>(
                            wpk + ((size_t)((w*4 + nt)*12 + gks)*64 + lane)*8);
                #pragma unroll
                for (int mt = 0; mt < 4; ++mt)
                    acc[nt][mt] = __builtin_amdgcn_mfma_f32_16x16x32_bf16(a[mt], b, acc[nt][mt], 0, 0, 0);
            }
        }
    }
    __syncthreads();

    // ------------- activation + write X to LDS in packed A-frag layout ------
    // D elem: row = mt*16+(lane>>4)*4+r, k2 = w*64+nt*16+(lane&15)
    #pragma unroll
    for (int nt = 0; nt < 4; ++nt)
        #pragma unroll
        for (int mt = 0; mt < 4; ++mt)
            #pragma unroll
            for (int r = 0; r < 4; ++r) {
                float xv = 1.7159f * fast_tanh(0.666f * acc[nt][mt][r]);
                int idx = ((mt*8 + w*2 + (nt >> 1)) * 64
                           + ((nt & 1)*2 + ((lane >> 3) & 1)) * 16 + (lane >> 4)*4 + r) * 8
                          + (lane & 7);
                lds[idx] = f2bf(xv);
            }
    __syncthreads();

    // ---------------- phase 2: 4 GEMMs over X + fused epilogue --------------
    const unsigned short* wmp = wpk + 98304;   // W1,W2,Wa,Wt each 65536 elems
    #pragma unroll 1
    for (int g = 0; g < 4; ++g) {              // n-tiles (16 cols each)
        const int n = w * 64 + g * 16 + (lane & 15);
        v4f a2[4][4];                          // [mat][mt]
        {
            float v1 = b1[n], v2 = b2[n], va = ba[n], vt = bt[n];
            v4f q1 = {v1,v1,v1,v1}, q2 = {v2,v2,v2,v2}, qa = {va,va,va,va}, qt = {vt,vt,vt,vt};
            #pragma unroll
            for (int mt = 0; mt < 4; ++mt) {
                a2[0][mt] = q1; a2[1][mt] = q2; a2[2][mt] = qa; a2[3][mt] = qt;
            }
        }
        #pragma unroll 1
        for (int ks = 0; ks < 8; ++ks) {
            v8s a[4];
            #pragma unroll
            for (int mt = 0; mt < 4; ++mt)
                a[mt] = *reinterpret_cast<const v8s*>(&lds[((mt*8 + ks)*64 + lane)*8]);
            const int tile = ((w*4 + g)*8 + ks)*64;
            #pragma unroll
            for (int mat = 0; mat < 4; ++mat) {
                v8s b = *reinterpret_cast<const v8s*>(wmp + (size_t)mat*65536 + ((size_t)tile + lane)*8);
                #pragma unroll
                for (int mt = 0; mt < 4; ++mt)
                    a2[mat][mt] = __builtin_amdgcn_mfma_f32_16x16x32_bf16(a[mt], b, a2[mat][mt], 0, 0, 0);
            }
        }
        // fused epilogue: ff1, ff2, t_interp, blend, store
        #pragma unroll
        for (int mt = 0; mt < 4; ++mt) {
            int rowb = row0 + mt*16 + ((lane >> 4) << 2);
            #pragma unroll
            for (int r = 0; r < 4; ++r) {
                float tsv = ts[rowb + r];
                float ff1 = fast_tanh(a2[0][mt][r]);
                float ff2 = fast_tanh(a2[1][mt][r]);
                float ti  = fast_sigmoid(a2[2][mt][r] * tsv + a2[3][mt][r]);
                out[(size_t)(rowb + r) * 256 + n] = ff1 + ti * (ff2 - ff1);
            }
        }
    }
}

extern "C" void kernel_launch(void* const* d_in, const int* in_sizes, int n_in,
                              void* d_out, int out_size, void* d_ws, size_t ws_size,
                              hipStream_t stream)
{
    const float* xin = (const float*)d_in[0];
    const float* hx  = (const float*)d_in[1];
    const float* ts  = (const float*)d_in[2];
    const float* Wb  = (const float*)d_in[3];
    const float* bb  = (const float*)d_in[4];
    const float* W1  = (const float*)d_in[5];
    const float* b1  = (const float*)d_in[6];
    const float* W2  = (const float*)d_in[7];
    const float* b2  = (const float*)d_in[8];
    const float* Wa  = (const float*)d_in[9];
    const float* ba  = (const float*)d_in[10];
    const float* Wt  = (const float*)d_in[11];
    const float* bt  = (const float*)d_in[12];

    if (ws_size < 360448 * sizeof(unsigned short)) return;
    unsigned short* wpk = (unsigned short*)d_ws;

    prep_pack<<<1408, 256, 0, stream>>>(Wb, W1, W2, Wa, Wt, wpk);
    cfc_fused<<<1024, 256, 0, stream>>>(xin, hx, ts, bb, b1, b2, ba, bt, wpk,
                                        (float*)d_out);
}